// Round 3
// baseline (368.915 us; speedup 1.0000x reference)
//
#include <hip/hip_runtime.h>

#define NN 100000
#define NE 1600000
#define FIN 256
#define FH 64
#define FC 16

#define SCAN_CHUNK 1024
#define NB_SCAN ((NN + SCAN_CHUNK - 1) / SCAN_CHUNK)   // 98
#define NB_COUNT ((NE / 4 + 255) / 256)                // 1563 (4 edges/thread)
#define NB_GEMM1 ((NN + 127) / 128)                    // 782 (128-row MFMA tiles)
#define NB_FUSED (3 * NB_GEMM1)                        // 2346: b%3==2 -> gemm, else count

typedef int v2i __attribute__((ext_vector_type(2)));
typedef int v4i __attribute__((ext_vector_type(4)));
typedef short s16x8 __attribute__((ext_vector_type(8)));   // 8 bf16 (4 VGPRs)
typedef float f32x4 __attribute__((ext_vector_type(4)));   // MFMA acc

__device__ __forceinline__ float4 fma4(float4 v, float w, float4 a) {
    a.x = fmaf(v.x, w, a.x); a.y = fmaf(v.y, w, a.y);
    a.z = fmaf(v.z, w, a.z); a.w = fmaf(v.w, w, a.w);
    return a;
}
__device__ __forceinline__ float4 add4(float4 a, float4 v) {
    a.x += v.x; a.y += v.y; a.z += v.z; a.w += v.w;
    return a;
}
__device__ __forceinline__ float4 xor_add4(float4 r, int m) {
    r.x += __shfl_xor(r.x, m, 64); r.y += __shfl_xor(r.y, m, 64);
    r.z += __shfl_xor(r.z, m, 64); r.w += __shfl_xor(r.w, m, 64);
    return r;
}

// RNE fp32 -> bf16 (top 16 bits)
__device__ __forceinline__ unsigned short bf16rne(float f) {
    unsigned u = __float_as_uint(f);
    u += 0x7FFFu + ((u >> 16) & 1u);
    return (unsigned short)(u >> 16);
}

// split 8 fp32 into bf16 hi + bf16 lo (hi+lo ~= fp32)
__device__ __forceinline__ void split8(const float* f, s16x8& hi, s16x8& lo) {
    #pragma unroll
    for (int i = 0; i < 8; i++) {
        unsigned u = __float_as_uint(f[i]);
        unsigned short h = (unsigned short)((u + 0x7FFFu + ((u >> 16) & 1u)) >> 16);
        float l = f[i] - __uint_as_float((unsigned)h << 16);
        unsigned ul = __float_as_uint(l);
        hi[i] = (short)h;
        lo[i] = (short)((ul + 0x7FFFu + ((ul >> 16) & 1u)) >> 16);
    }
}

// ---- PREP: W1 -> MFMA B-fragment layout (bf16 hi/lo) + int64 detect --------
// B-frag for mfma_f32_16x16x32_bf16: lane l holds W[k0+(l>>4)*8+i][n0+(l&15)]
// flattened: Wf[((s*4 + c)*64 + l)*8 + i],  s=K-step (k0=32s), c=col-frag (n0=16c)
__global__ __launch_bounds__(256) void prep_k(const int* __restrict__ ei,
                                              int* __restrict__ flag,
                                              const float* __restrict__ W,
                                              unsigned short* __restrict__ Whi,
                                              unsigned short* __restrict__ Wlo) {
    int b = blockIdx.x;
    if (b == 8) {
        if (threadIdx.x == 0) {
            int z = (ei[1] == 0) & (ei[3] == 0) & (ei[5] == 0) & (ei[7] == 0);
            *flag = z;   // 1 => int64 layout, 0 => int32 layout
        }
        return;
    }
    int slot = b * 256 + threadIdx.x;      // 0..2047 = (s,c,l)
    int l = slot & 63;
    int c = (slot >> 6) & 3;
    int s = slot >> 8;
    int k0 = s * 32 + (l >> 4) * 8;
    int col = c * 16 + (l & 15);
    #pragma unroll
    for (int i = 0; i < 8; i++) {
        float f = W[(k0 + i) * FH + col];
        unsigned short h = bf16rne(f);
        float lres = f - __uint_as_float((unsigned)h << 16);
        Whi[slot * 8 + i] = h;
        Wlo[slot * 8 + i] = bf16rne(lres);
    }
}

// ---- FUSED: count+rank+pack || GEMM1(MFMA), roles INTERLEAVED (b%3==2) -----
// Count role: 4 edges/thread -> 4 independent load->atomic->store chains in
// flight per thread (the round-1 bottleneck was MLP=1 on a ~1800cy chain).
__global__ __launch_bounds__(256, 4) void fused_k(const int* __restrict__ ei,
                                                  const int* __restrict__ flag,
                                                  int* __restrict__ deg,
                                                  v2i* __restrict__ packed,
                                                  const float* __restrict__ x,
                                                  const unsigned short* __restrict__ Whi,
                                                  const unsigned short* __restrict__ Wlo,
                                                  float* __restrict__ h1) {
    const int b = blockIdx.x;
    if ((b % 3) != 2) {                       // ---- count role ----
        int cb = (b / 3) * 2 + (b % 3);
        if (cb >= NB_COUNT) return;
        int e = (cb * 256 + threadIdx.x) * 4;
        if (e >= NE) return;                  // NE%4==0 -> e..e+3 all valid
        int f = *flag;
        int s0, s1, s2, s3, d0, d1, d2, d3;
        if (f) {                              // int64: ints at 2*pos (low words)
            v4i a = *(const v4i*)&ei[2 * e];
            v4i b2 = *(const v4i*)&ei[2 * e + 4];
            s0 = a.x; s1 = a.z; s2 = b2.x; s3 = b2.z;
            v4i c = *(const v4i*)&ei[2 * (NE + e)];
            v4i d = *(const v4i*)&ei[2 * (NE + e) + 4];
            d0 = c.x; d1 = c.z; d2 = d.x; d3 = d.z;
        } else {                              // int32
            v4i a = *(const v4i*)&ei[e];
            s0 = a.x; s1 = a.y; s2 = a.z; s3 = a.w;
            v4i c = *(const v4i*)&ei[NE + e];
            d0 = c.x; d1 = c.y; d2 = c.z; d3 = c.w;
        }
        int r0 = atomicAdd(&deg[d0], 1);
        int r1 = atomicAdd(&deg[d1], 1);
        int r2 = atomicAdd(&deg[d2], 1);
        int r3 = atomicAdd(&deg[d3], 1);
        v4i pa, pb;
        pa.x = s0; pa.y = d0 | (r0 << 17);    // dst<2^17, rank<2^12
        pa.z = s1; pa.w = d1 | (r1 << 17);
        pb.x = s2; pb.y = d2 | (r2 << 17);
        pb.z = s3; pb.w = d3 | (r3 << 17);
        *(v4i*)&packed[e] = pa;
        *(v4i*)&packed[e + 2] = pb;
        return;
    }
    // ---- GEMM1 role: h1[NN][64] = x[NN][256] @ W1, 128-row tile, MFMA ------
    const int t = threadIdx.x;
    const int lane = t & 63;
    const int wid = t >> 6;
    const int mb = (b / 3) * 128 + wid * 32;  // wave's 32-row sub-tile
    const int lr = lane & 15;                 // A row-in-frag / D col
    const int lk = (lane >> 4) * 8;           // k offset within K-step

    int ra0 = mb + lr;
    int ra1 = mb + 16 + lr;
    const float* pa0 = x + (size_t)(ra0 < NN ? ra0 : NN - 1) * FIN + lk;
    const float* pa1 = x + (size_t)(ra1 < NN ? ra1 : NN - 1) * FIN + lk;

    f32x4 acc[2][4] = {};

    for (int s = 0; s < 8; s++) {             // K-steps of 32
        float fa0[8], fa1[8];
        float4 q;
        q = *(const float4*)(pa0 + s * 32);
        fa0[0] = q.x; fa0[1] = q.y; fa0[2] = q.z; fa0[3] = q.w;
        q = *(const float4*)(pa0 + s * 32 + 4);
        fa0[4] = q.x; fa0[5] = q.y; fa0[6] = q.z; fa0[7] = q.w;
        q = *(const float4*)(pa1 + s * 32);
        fa1[0] = q.x; fa1[1] = q.y; fa1[2] = q.z; fa1[3] = q.w;
        q = *(const float4*)(pa1 + s * 32 + 4);
        fa1[4] = q.x; fa1[5] = q.y; fa1[6] = q.z; fa1[7] = q.w;

        s16x8 a0h, a0l, a1h, a1l;
        split8(fa0, a0h, a0l);
        split8(fa1, a1h, a1l);

        #pragma unroll
        for (int c = 0; c < 4; c++) {
            s16x8 wh = *(const s16x8*)&Whi[((s * 4 + c) * 64 + lane) * 8];
            s16x8 wl = *(const s16x8*)&Wlo[((s * 4 + c) * 64 + lane) * 8];
            acc[0][c] = __builtin_amdgcn_mfma_f32_16x16x32_bf16(a0h, wh, acc[0][c], 0, 0, 0);
            acc[0][c] = __builtin_amdgcn_mfma_f32_16x16x32_bf16(a0l, wh, acc[0][c], 0, 0, 0);
            acc[0][c] = __builtin_amdgcn_mfma_f32_16x16x32_bf16(a0h, wl, acc[0][c], 0, 0, 0);
            acc[1][c] = __builtin_amdgcn_mfma_f32_16x16x32_bf16(a1h, wh, acc[1][c], 0, 0, 0);
            acc[1][c] = __builtin_amdgcn_mfma_f32_16x16x32_bf16(a1l, wh, acc[1][c], 0, 0, 0);
            acc[1][c] = __builtin_amdgcn_mfma_f32_16x16x32_bf16(a1h, wl, acc[1][c], 0, 0, 0);
        }
    }
    // D layout: col = lane&15, row = (lane>>4)*4 + v   [m89-verified]
    #pragma unroll
    for (int r = 0; r < 2; r++) {
        int rowb = mb + 16 * r + (lane >> 4) * 4;
        #pragma unroll
        for (int c = 0; c < 4; c++) {
            #pragma unroll
            for (int v = 0; v < 4; v++) {
                int row = rowb + v;
                if (row < NN)
                    h1[(size_t)row * FH + 16 * c + lr] = acc[r][c][v];
            }
        }
    }
}

// ---- scan pass 1 + dinv + h1 prescale (scale1 fused in, coalesced) ---------
__global__ __launch_bounds__(256) void scan_sum_k(const int* __restrict__ deg,
                                                  int* __restrict__ partial,
                                                  float* __restrict__ dinv,
                                                  float* __restrict__ h1) {
    __shared__ int red[256];
    __shared__ float sdv[SCAN_CHUNK];      // 4 KB
    int b = blockIdx.x, t = threadIdx.x;
    int base = b * SCAN_CHUNK + t * 4;
    int s = 0;
    #pragma unroll
    for (int i = 0; i < 4; i++) {
        int idx = base + i;
        float dv = 0.f;
        if (idx < NN) {
            int d = deg[idx];
            s += d;
            dv = rsqrtf((float)(d + 1));   // +1 self-loop
            dinv[idx] = dv;
        }
        sdv[t * 4 + i] = dv;
    }
    red[t] = s;
    __syncthreads();
    // scale h1 rows [b*1024, b*1024+1024): 16 threads/row -> fully coalesced
    #pragma unroll 4
    for (int it = 0; it < 64; it++) {
        int q = it * 256 + t;              // 0..16383
        int rl = q >> 4;                   // local row
        int row = b * SCAN_CHUNK + rl;
        if (row < NN) {
            float d = sdv[rl];
            float4 v = *(const float4*)&h1[(size_t)row * FH + (q & 15) * 4];
            v.x *= d; v.y *= d; v.z *= d; v.w *= d;
            *(float4*)&h1[(size_t)row * FH + (q & 15) * 4] = v;
        }
    }
    for (int off = 128; off > 0; off >>= 1) {
        if (t < off) red[t] += red[t + off];
        __syncthreads();
    }
    if (t == 0) partial[b] = red[0];
}

// ---- pass 2: single small block exclusive-scans the partials ---------------
__global__ __launch_bounds__(128) void scan_part_k(int* __restrict__ partial) {
    __shared__ int s[128];
    int t = threadIdx.x;
    int v = (t < NB_SCAN) ? partial[t] : 0;
    s[t] = v; __syncthreads();
    for (int off = 1; off < 128; off <<= 1) {
        int u = (t >= off) ? s[t - off] : 0;
        __syncthreads();
        s[t] += u;
        __syncthreads();
    }
    if (t < NB_SCAN) partial[t] = s[t] - v;   // exclusive
}

// ---- pass 3: per-block local scan + offset -> row_start --------------------
__global__ __launch_bounds__(256) void scan_out_k(const int* __restrict__ deg,
                                                  const int* __restrict__ partial,
                                                  int* __restrict__ row_start) {
    __shared__ int s[256];
    int b = blockIdx.x, t = threadIdx.x;
    int base = b * SCAN_CHUNK + t * 4;
    int v[4]; int sum = 0;
    #pragma unroll
    for (int i = 0; i < 4; i++) {
        int idx = base + i;
        v[i] = (idx < NN) ? deg[idx] : 0;
        sum += v[i];
    }
    s[t] = sum; __syncthreads();
    for (int off = 1; off < 256; off <<= 1) {
        int u = (t >= off) ? s[t - off] : 0;
        __syncthreads();
        s[t] += u;
        __syncthreads();
    }
    int run = partial[b] + s[t] - sum;
    #pragma unroll
    for (int i = 0; i < 4; i++) {
        int idx = base + i;
        if (idx < NN) {
            row_start[idx] = run;
            run += v[i];
            if (idx == NN - 1) row_start[NN] = run;   // == NE
        }
    }
}

// ---- CSR fill: 2 edges/thread, pure store, no atomic -----------------------
__global__ __launch_bounds__(256) void fill_k(const int* __restrict__ packed,
                                              const int* __restrict__ row_start,
                                              int* __restrict__ csr) {
    int e = (blockIdx.x * 256 + threadIdx.x) * 2;
    if (e >= NE) return;                      // NE%2==0
    v4i p = __builtin_nontemporal_load((const v4i*)&packed[2 * e]);
    int d0 = p.y & 0x1FFFF;
    int r0 = ((unsigned)p.y) >> 17;
    int d1 = p.w & 0x1FFFF;
    int r1 = ((unsigned)p.w) >> 17;
    csr[row_start[d0] + r0] = p.x;
    csr[row_start[d1] + r1] = p.z;
}

// ---- FUSED agg1 + relu + GEMM2 (h1 prescaled; h2' = dinv*h2 stored) --------
__global__ __launch_bounds__(256) void agg1g_k(const int* __restrict__ csr,
                                               const int* __restrict__ row_start,
                                               const float* __restrict__ h1,
                                               const float* __restrict__ dinv,
                                               const float* __restrict__ b1,
                                               const float* __restrict__ W2,
                                               float* __restrict__ h2) {
    __shared__ float sW2[FH * FC];     // 4 KB
    __shared__ float sp[4][FH];        // per-wave relu'd agg row
    const int t = threadIdx.x;
    #pragma unroll
    for (int i = 0; i < 4; i++) sW2[t + 256 * i] = W2[t + 256 * i];
    __syncthreads();

    int wid = t >> 6;
    int n = blockIdx.x * 4 + wid;
    int lane = t & 63;
    if (n >= NN) return;
    int sg = lane >> 4;        // edge slot 0..3
    int fl = lane & 15;        // feature quad 0..15
    int s0 = row_start[n], s1 = row_start[n + 1];
    float4 A = make_float4(0.f, 0.f, 0.f, 0.f);
    float4 B = make_float4(0.f, 0.f, 0.f, 0.f);
    float4 C = make_float4(0.f, 0.f, 0.f, 0.f);
    float4 D = make_float4(0.f, 0.f, 0.f, 0.f);
    for (int j0 = s0; j0 < s1; j0 += 64) {
        int idx = j0 + lane;
        int sl = (idx < s1) ? csr[idx] : 0;
        int cnt = s1 - j0; if (cnt > 64) cnt = 64;
        int j = 0;
        for (; j + 16 <= cnt; j += 16) {
            int eA = __shfl(sl, j + sg, 64);
            int eB = __shfl(sl, j + 4 + sg, 64);
            int eC = __shfl(sl, j + 8 + sg, 64);
            int eD = __shfl(sl, j + 12 + sg, 64);
            float4 vA = *(const float4*)&h1[eA * FH + fl * 4];
            float4 vB = *(const float4*)&h1[eB * FH + fl * 4];
            float4 vC = *(const float4*)&h1[eC * FH + fl * 4];
            float4 vD = *(const float4*)&h1[eD * FH + fl * 4];
            A = add4(A, vA); B = add4(B, vB);
            C = add4(C, vC); D = add4(D, vD);
        }
        if (j + 8 <= cnt) {
            int eA = __shfl(sl, j + sg, 64);
            int eB = __shfl(sl, j + 4 + sg, 64);
            float4 vA = *(const float4*)&h1[eA * FH + fl * 4];
            float4 vB = *(const float4*)&h1[eB * FH + fl * 4];
            A = add4(A, vA); B = add4(B, vB);
            j += 8;
        }
        if (j + 4 <= cnt) {
            int eA = __shfl(sl, j + sg, 64);
            float4 vA = *(const float4*)&h1[eA * FH + fl * 4];
            A = add4(A, vA);
            j += 4;
        }
        int rem = cnt - j;
        if (rem > 0) {                      // 1..3 edges, mask extra slots
            int jj = j + (sg < rem ? sg : 0);
            int eA = __shfl(sl, jj, 64);
            float wA = (sg < rem) ? 1.f : 0.f;
            float4 vA = *(const float4*)&h1[eA * FH + fl * 4];
            A = fma4(vA, wA, A);
        }
    }
    float4 r = add4(add4(A, B), add4(C, D));
    r = xor_add4(r, 16);
    r = xor_add4(r, 32);                    // all lanes hold full quad sum
    float dn = dinv[n];
    if (sg == 0) {
        float4 self = *(const float4*)&h1[n * FH + fl * 4];   // h1' already scaled
        float4 bq = *(const float4*)&b1[fl * 4];
        float4 p;
        p.x = fmaxf(fmaf(r.x + self.x, dn, bq.x), 0.f);
        p.y = fmaxf(fmaf(r.y + self.y, dn, bq.y), 0.f);
        p.z = fmaxf(fmaf(r.z + self.z, dn, bq.z), 0.f);
        p.w = fmaxf(fmaf(r.w + self.w, dn, bq.w), 0.f);
        *(float4*)&sp[wid][fl * 4] = p;     // wave-local LDS
    }
    __builtin_amdgcn_s_waitcnt(0);          // drain lgkm within wave
    if (lane < FC) {
        float o = 0.f;
        #pragma unroll 8
        for (int k = 0; k < FH; k++)
            o = fmaf(sp[wid][k], sW2[k * FC + lane], o);
        h2[n * FC + lane] = o * dn;         // store h2' = dinv*h2
    }
}

// ---- agg layer2 (h2' prescaled): 16-lane subgroup/node, 16 edges in flight -
__global__ __launch_bounds__(256) void agg2_k(const int* __restrict__ csr,
                                              const int* __restrict__ row_start,
                                              const float* __restrict__ h2,
                                              const float* __restrict__ dinv,
                                              const float* __restrict__ b2,
                                              float* __restrict__ out) {
    const int t = threadIdx.x;
    int n = blockIdx.x * 16 + (t >> 4);
    int l16 = t & 15;
    int base = t & 48;          // subgroup base lane in wave
    int q = (t >> 2) & 3;       // edge slot
    int c = t & 3;              // feature quad
    if (n >= NN) return;
    int s0 = row_start[n], s1 = row_start[n + 1];
    float4 A = make_float4(0.f, 0.f, 0.f, 0.f);
    float4 B = make_float4(0.f, 0.f, 0.f, 0.f);
    float4 C = make_float4(0.f, 0.f, 0.f, 0.f);
    float4 D = make_float4(0.f, 0.f, 0.f, 0.f);
    for (int j0 = s0; j0 < s1; j0 += 16) {
        int idx = j0 + l16;
        int sl = (idx < s1) ? csr[idx] : 0;
        int cnt = s1 - j0; if (cnt > 16) cnt = 16;
        int j = 0;
        if (j + 16 <= cnt) {
            int eA = __shfl(sl, base + j + q, 64);
            int eB = __shfl(sl, base + j + 4 + q, 64);
            int eC = __shfl(sl, base + j + 8 + q, 64);
            int eD = __shfl(sl, base + j + 12 + q, 64);
            float4 vA = *(const float4*)&h2[eA * FC + c * 4];
            float4 vB = *(const float4*)&h2[eB * FC + c * 4];
            float4 vC = *(const float4*)&h2[eC * FC + c * 4];
            float4 vD = *(const float4*)&h2[eD * FC + c * 4];
            A = add4(A, vA); B = add4(B, vB);
            C = add4(C, vC); D = add4(D, vD);
            j += 16;
        }
        if (j + 8 <= cnt) {
            int eA = __shfl(sl, base + j + q, 64);
            int eB = __shfl(sl, base + j + 4 + q, 64);
            float4 vA = *(const float4*)&h2[eA * FC + c * 4];
            float4 vB = *(const float4*)&h2[eB * FC + c * 4];
            A = add4(A, vA); B = add4(B, vB);
            j += 8;
        }
        if (j + 4 <= cnt) {
            int eA = __shfl(sl, base + j + q, 64);
            float4 vA = *(const float4*)&h2[eA * FC + c * 4];
            A = add4(A, vA);
            j += 4;
        }
        int rem = cnt - j;
        if (rem > 0) {
            int jj = base + j + (q < rem ? q : 0);
            int eA = __shfl(sl, jj, 64);
            float wA = (q < rem) ? 1.f : 0.f;
            float4 vA = *(const float4*)&h2[eA * FC + c * 4];
            A = fma4(vA, wA, A);
        }
    }
    float4 r = add4(add4(A, B), add4(C, D));
    r = xor_add4(r, 4);
    r = xor_add4(r, 8);                     // reduce across q within subgroup
    if (q == 0) {
        float dn = dinv[n];
        float4 self = *(const float4*)&h2[n * FC + c * 4];    // h2' already scaled
        float4 bq = *(const float4*)&b2[c * 4];
        float4 p;
        p.x = fmaf(r.x + self.x, dn, bq.x);
        p.y = fmaf(r.y + self.y, dn, bq.y);
        p.z = fmaf(r.z + self.z, dn, bq.z);
        p.w = fmaf(r.w + self.w, dn, bq.w);
        *(float4*)&out[n * FC + c * 4] = p;
    }
}

extern "C" void kernel_launch(void* const* d_in, const int* in_sizes, int n_in,
                              void* d_out, int out_size, void* d_ws, size_t ws_size,
                              hipStream_t stream) {
    const float* x  = (const float*)d_in[0];
    const int*   ei = (const int*)d_in[1];
    const float* W1 = (const float*)d_in[2];
    const float* b1 = (const float*)d_in[3];
    const float* W2 = (const float*)d_in[4];
    const float* b2 = (const float*)d_in[5];
    float* out = (float*)d_out;

    char* ws = (char*)d_ws;
    int*   deg       = (int*)(ws + 0);                       // 400 KB
    int*   row_start = (int*)(ws + 512 * 1024);              // 400 KB + 4
    float* dinv      = (float*)(ws + 1024 * 1024);           // 400 KB
    int*   flag      = (int*)(ws + 1536 * 1024);             // 4 B
    int*   partial   = (int*)(ws + 1540 * 1024);             // 392 B
    unsigned short* Whi = (unsigned short*)(ws + 1544 * 1024); // 32 KB (W1 bf16 hi frags)
    unsigned short* Wlo = (unsigned short*)(ws + 1584 * 1024); // 32 KB (W1 bf16 lo frags)
    int*   csr       = (int*)(ws + 2ull * 1024 * 1024);      // 6.4 MB  [fill..agg2]
    float* h1        = (float*)(ws + 9ull * 1024 * 1024);    // 25.6 MB [fused..agg1g]
    v2i*   packed    = (v2i*)(ws + 35ull * 1024 * 1024);     // 12.8 MB [fused..fill]
    float* h2        = (float*)(ws + 35ull * 1024 * 1024);   // 6.4 MB  [agg1g..agg2]
                                                             //   aliases packed (dead)

    prep_k<<<9, 256, 0, stream>>>(ei, flag, W1, Whi, Wlo);
    (void)hipMemsetAsync(deg, 0, NN * sizeof(int), stream);
    fused_k<<<NB_FUSED, 256, 0, stream>>>(ei, flag, deg, packed, x, Whi, Wlo, h1);
    scan_sum_k<<<NB_SCAN, 256, 0, stream>>>(deg, partial, dinv, h1);
    scan_part_k<<<1, 128, 0, stream>>>(partial);
    scan_out_k<<<NB_SCAN, 256, 0, stream>>>(deg, partial, row_start);
    fill_k<<<(NE / 2 + 255) / 256, 256, 0, stream>>>((const int*)packed, row_start, csr);

    agg1g_k<<<(NN + 3) / 4, 256, 0, stream>>>(csr, row_start, h1, dinv, b1, W2, h2);
    agg2_k<<<(NN + 15) / 16, 256, 0, stream>>>(csr, row_start, h2, dinv, b2, out);
}

// Round 4
// 364.408 us; speedup vs baseline: 1.0124x; 1.0124x over previous
//
#include <hip/hip_runtime.h>

#define NN 100000
#define NE 1600000
#define FIN 256
#define FH 64
#define FC 16
#define K_REP 8

#define NB_SCAN2 ((NN + 255) / 256)                    // 391 (256 nodes/block)
#define NB_COUNT ((NE / 4 + 255) / 256)                // 1563 (4 edges/thread)
#define NB_GEMM1 ((NN + 127) / 128)                    // 782 (128-row MFMA tiles)
#define NB_FUSED (3 * NB_GEMM1)                        // 2346: b%3==2 -> gemm, else count

typedef int v2i __attribute__((ext_vector_type(2)));
typedef int v4i __attribute__((ext_vector_type(4)));
typedef short s16x8 __attribute__((ext_vector_type(8)));   // 8 bf16 (4 VGPRs)
typedef float f32x4 __attribute__((ext_vector_type(4)));   // MFMA acc

__device__ __forceinline__ float4 fma4(float4 v, float w, float4 a) {
    a.x = fmaf(v.x, w, a.x); a.y = fmaf(v.y, w, a.y);
    a.z = fmaf(v.z, w, a.z); a.w = fmaf(v.w, w, a.w);
    return a;
}
__device__ __forceinline__ float4 add4(float4 a, float4 v) {
    a.x += v.x; a.y += v.y; a.z += v.z; a.w += v.w;
    return a;
}
__device__ __forceinline__ float4 xor_add4(float4 r, int m) {
    r.x += __shfl_xor(r.x, m, 64); r.y += __shfl_xor(r.y, m, 64);
    r.z += __shfl_xor(r.z, m, 64); r.w += __shfl_xor(r.w, m, 64);
    return r;
}

// RNE fp32 -> bf16 (top 16 bits)
__device__ __forceinline__ unsigned short bf16rne(float f) {
    unsigned u = __float_as_uint(f);
    u += 0x7FFFu + ((u >> 16) & 1u);
    return (unsigned short)(u >> 16);
}

// split 8 fp32 into bf16 hi + bf16 lo (hi+lo ~= fp32)
__device__ __forceinline__ void split8(const float* f, s16x8& hi, s16x8& lo) {
    #pragma unroll
    for (int i = 0; i < 8; i++) {
        unsigned u = __float_as_uint(f[i]);
        unsigned short h = (unsigned short)((u + 0x7FFFu + ((u >> 16) & 1u)) >> 16);
        float l = f[i] - __uint_as_float((unsigned)h << 16);
        unsigned ul = __float_as_uint(l);
        hi[i] = (short)h;
        lo[i] = (short)((ul + 0x7FFFu + ((ul >> 16) & 1u)) >> 16);
    }
}

// ---- PREP: W1 -> MFMA B-fragment layout (bf16 hi/lo) + int64 detect --------
// B-frag for mfma_f32_16x16x32_bf16: lane l holds W[k0+(l>>4)*8+i][n0+(l&15)]
// flattened: Wf[((s*4 + c)*64 + l)*8 + i],  s=K-step (k0=32s), c=col-frag (n0=16c)
__global__ __launch_bounds__(256) void prep_k(const int* __restrict__ ei,
                                              int* __restrict__ flag,
                                              const float* __restrict__ W,
                                              unsigned short* __restrict__ Whi,
                                              unsigned short* __restrict__ Wlo) {
    int b = blockIdx.x;
    if (b == 8) {
        if (threadIdx.x == 0) {
            int z = (ei[1] == 0) & (ei[3] == 0) & (ei[5] == 0) & (ei[7] == 0);
            *flag = z;   // 1 => int64 layout, 0 => int32 layout
        }
        return;
    }
    int slot = b * 256 + threadIdx.x;      // 0..2047 = (s,c,l)
    int l = slot & 63;
    int c = (slot >> 6) & 3;
    int s = slot >> 8;
    int k0 = s * 32 + (l >> 4) * 8;
    int col = c * 16 + (l & 15);
    #pragma unroll
    for (int i = 0; i < 8; i++) {
        float f = W[(k0 + i) * FH + col];
        unsigned short h = bf16rne(f);
        float lres = f - __uint_as_float((unsigned)h << 16);
        Whi[slot * 8 + i] = h;
        Wlo[slot * 8 + i] = bf16rne(lres);
    }
}

// ---- FUSED: count+rank+pack || GEMM1(MFMA), roles INTERLEAVED (b%3==2) -----
// Count role: 8-replica degree histogram deg2[k*NN+n] (replica-major => 8x the
// 32B sectors => 8x less same-sector atomic serialization at the coherence pt).
// packed.y = dst(17) | k(3) | rank_in_replica(12).
__global__ __launch_bounds__(256, 4) void fused_k(const int* __restrict__ ei,
                                                  const int* __restrict__ flag,
                                                  int* __restrict__ deg2,
                                                  v2i* __restrict__ packed,
                                                  const float* __restrict__ x,
                                                  const unsigned short* __restrict__ Whi,
                                                  const unsigned short* __restrict__ Wlo,
                                                  float* __restrict__ h1) {
    const int b = blockIdx.x;
    if ((b % 3) != 2) {                       // ---- count role ----
        int cb = (b / 3) * 2 + (b % 3);
        if (cb >= NB_COUNT) return;
        int e = (cb * 256 + threadIdx.x) * 4;
        if (e >= NE) return;                  // NE%4==0 -> e..e+3 all valid
        int kk = ((cb << 2) | (threadIdx.x >> 6)) & 7;   // per-wave replica
        int f = *flag;
        int s0, s1, s2, s3, d0, d1, d2, d3;
        if (f) {                              // int64: ints at 2*pos (low words)
            v4i a = *(const v4i*)&ei[2 * e];
            v4i b2 = *(const v4i*)&ei[2 * e + 4];
            s0 = a.x; s1 = a.z; s2 = b2.x; s3 = b2.z;
            v4i c = *(const v4i*)&ei[2 * (NE + e)];
            v4i d = *(const v4i*)&ei[2 * (NE + e) + 4];
            d0 = c.x; d1 = c.z; d2 = d.x; d3 = d.z;
        } else {                              // int32
            v4i a = *(const v4i*)&ei[e];
            s0 = a.x; s1 = a.y; s2 = a.z; s3 = a.w;
            v4i c = *(const v4i*)&ei[NE + e];
            d0 = c.x; d1 = c.y; d2 = c.z; d3 = c.w;
        }
        int* dg = deg2 + kk * NN;
        int r0 = atomicAdd(&dg[d0], 1);
        int r1 = atomicAdd(&dg[d1], 1);
        int r2 = atomicAdd(&dg[d2], 1);
        int r3 = atomicAdd(&dg[d3], 1);
        int kb = kk << 17;
        v4i pa, pb;
        pa.x = s0; pa.y = d0 | kb | (r0 << 20);
        pa.z = s1; pa.w = d1 | kb | (r1 << 20);
        pb.x = s2; pb.y = d2 | kb | (r2 << 20);
        pb.z = s3; pb.w = d3 | kb | (r3 << 20);
        *(v4i*)&packed[e] = pa;
        *(v4i*)&packed[e + 2] = pb;
        return;
    }
    // ---- GEMM1 role: h1[NN][64] = x[NN][256] @ W1, 128-row tile, MFMA ------
    const int t = threadIdx.x;
    const int lane = t & 63;
    const int wid = t >> 6;
    const int mb = (b / 3) * 128 + wid * 32;  // wave's 32-row sub-tile
    const int lr = lane & 15;                 // A row-in-frag / D col
    const int lk = (lane >> 4) * 8;           // k offset within K-step

    int ra0 = mb + lr;
    int ra1 = mb + 16 + lr;
    const float* pa0 = x + (size_t)(ra0 < NN ? ra0 : NN - 1) * FIN + lk;
    const float* pa1 = x + (size_t)(ra1 < NN ? ra1 : NN - 1) * FIN + lk;

    f32x4 acc[2][4] = {};

    for (int s = 0; s < 8; s++) {             // K-steps of 32
        float fa0[8], fa1[8];
        float4 q;
        q = *(const float4*)(pa0 + s * 32);
        fa0[0] = q.x; fa0[1] = q.y; fa0[2] = q.z; fa0[3] = q.w;
        q = *(const float4*)(pa0 + s * 32 + 4);
        fa0[4] = q.x; fa0[5] = q.y; fa0[6] = q.z; fa0[7] = q.w;
        q = *(const float4*)(pa1 + s * 32);
        fa1[0] = q.x; fa1[1] = q.y; fa1[2] = q.z; fa1[3] = q.w;
        q = *(const float4*)(pa1 + s * 32 + 4);
        fa1[4] = q.x; fa1[5] = q.y; fa1[6] = q.z; fa1[7] = q.w;

        s16x8 a0h, a0l, a1h, a1l;
        split8(fa0, a0h, a0l);
        split8(fa1, a1h, a1l);

        #pragma unroll
        for (int c = 0; c < 4; c++) {
            s16x8 wh = *(const s16x8*)&Whi[((s * 4 + c) * 64 + lane) * 8];
            s16x8 wl = *(const s16x8*)&Wlo[((s * 4 + c) * 64 + lane) * 8];
            acc[0][c] = __builtin_amdgcn_mfma_f32_16x16x32_bf16(a0h, wh, acc[0][c], 0, 0, 0);
            acc[0][c] = __builtin_amdgcn_mfma_f32_16x16x32_bf16(a0l, wh, acc[0][c], 0, 0, 0);
            acc[0][c] = __builtin_amdgcn_mfma_f32_16x16x32_bf16(a0h, wl, acc[0][c], 0, 0, 0);
            acc[1][c] = __builtin_amdgcn_mfma_f32_16x16x32_bf16(a1h, wh, acc[1][c], 0, 0, 0);
            acc[1][c] = __builtin_amdgcn_mfma_f32_16x16x32_bf16(a1l, wh, acc[1][c], 0, 0, 0);
            acc[1][c] = __builtin_amdgcn_mfma_f32_16x16x32_bf16(a1h, wl, acc[1][c], 0, 0, 0);
        }
    }
    // D layout: col = lane&15, row = (lane>>4)*4 + v   [m89-verified]
    #pragma unroll
    for (int r = 0; r < 2; r++) {
        int rowb = mb + 16 * r + (lane >> 4) * 4;
        #pragma unroll
        for (int c = 0; c < 4; c++) {
            #pragma unroll
            for (int v = 0; v < 4; v++) {
                int row = rowb + v;
                if (row < NN)
                    h1[(size_t)row * FH + 16 * c + lr] = acc[r][c][v];
            }
        }
    }
}

// ---- scan pass 1 + dinv + h1 prescale: 256 nodes (=2048 scan entries)/block -
__global__ __launch_bounds__(256) void scan_sum_k(const int* __restrict__ deg2,
                                                  int* __restrict__ partial,
                                                  float* __restrict__ dinv,
                                                  float* __restrict__ h1) {
    __shared__ int red[256];
    __shared__ float sdv[256];
    int b = blockIdx.x, t = threadIdx.x;
    int n = b * 256 + t;
    int sum = 0;
    float dv = 0.f;
    if (n < NN) {
        #pragma unroll
        for (int k = 0; k < K_REP; k++) sum += deg2[k * NN + n];
        dv = rsqrtf((float)(sum + 1));   // +1 self-loop
        dinv[n] = dv;
    }
    sdv[t] = dv;
    red[t] = sum;
    __syncthreads();
    // prescale h1 rows [b*256, b*256+256): 16 threads/row, fully coalesced
    #pragma unroll 4
    for (int it = 0; it < 16; it++) {
        int q = it * 256 + t;              // 0..4095
        int rl = q >> 4;                   // local row
        int row = b * 256 + rl;
        if (row < NN) {
            float d = sdv[rl];
            float4 v = *(const float4*)&h1[(size_t)row * FH + (q & 15) * 4];
            v.x *= d; v.y *= d; v.z *= d; v.w *= d;
            *(float4*)&h1[(size_t)row * FH + (q & 15) * 4] = v;
        }
    }
    for (int off = 128; off > 0; off >>= 1) {
        if (t < off) red[t] += red[t + off];
        __syncthreads();
    }
    if (t == 0) partial[b] = red[0];
}

// ---- pass 2: single block exclusive-scans the 391 partials -----------------
__global__ __launch_bounds__(512) void scan_part_k(int* __restrict__ partial) {
    __shared__ int s[512];
    int t = threadIdx.x;
    int v = (t < NB_SCAN2) ? partial[t] : 0;
    s[t] = v; __syncthreads();
    for (int off = 1; off < 512; off <<= 1) {
        int u = (t >= off) ? s[t - off] : 0;
        __syncthreads();
        s[t] += u;
        __syncthreads();
    }
    if (t < NB_SCAN2) partial[t] = s[t] - v;   // exclusive
}

// ---- pass 3: row_start[(n,k)] in n-major order -> node rows stay contiguous -
__global__ __launch_bounds__(256) void scan_out_k(const int* __restrict__ deg2,
                                                  const int* __restrict__ partial,
                                                  int* __restrict__ row_start) {
    __shared__ int s[256];
    int b = blockIdx.x, t = threadIdx.x;
    int n = b * 256 + t;
    int v[K_REP]; int sum = 0;
    #pragma unroll
    for (int k = 0; k < K_REP; k++) {
        v[k] = (n < NN) ? deg2[k * NN + n] : 0;
        sum += v[k];
    }
    s[t] = sum; __syncthreads();
    for (int off = 1; off < 256; off <<= 1) {
        int u = (t >= off) ? s[t - off] : 0;
        __syncthreads();
        s[t] += u;
        __syncthreads();
    }
    int run = partial[b] + s[t] - sum;
    if (n < NN) {
        #pragma unroll
        for (int k = 0; k < K_REP; k++) {
            row_start[n * K_REP + k] = run;
            run += v[k];
        }
        if (n == NN - 1) row_start[NN * K_REP] = run;   // == NE
    }
}

// ---- CSR fill: 2 edges/thread, pure store, no atomic -----------------------
__global__ __launch_bounds__(256) void fill_k(const int* __restrict__ packed,
                                              const int* __restrict__ row_start,
                                              int* __restrict__ csr) {
    int e = (blockIdx.x * 256 + threadIdx.x) * 2;
    if (e >= NE) return;                      // NE%2==0
    v4i p = __builtin_nontemporal_load((const v4i*)&packed[2 * e]);
    int d0 = p.y & 0x1FFFF;
    int k0 = (p.y >> 17) & 7;
    int r0 = ((unsigned)p.y) >> 20;
    int d1 = p.w & 0x1FFFF;
    int k1 = (p.w >> 17) & 7;
    int r1 = ((unsigned)p.w) >> 20;
    csr[row_start[d0 * K_REP + k0] + r0] = p.x;
    csr[row_start[d1 * K_REP + k1] + r1] = p.z;
}

// ---- FUSED agg1 + relu + GEMM2 (h1 prescaled; h2' = dinv*h2 stored) --------
__global__ __launch_bounds__(256) void agg1g_k(const int* __restrict__ csr,
                                               const int* __restrict__ row_start,
                                               const float* __restrict__ h1,
                                               const float* __restrict__ dinv,
                                               const float* __restrict__ b1,
                                               const float* __restrict__ W2,
                                               float* __restrict__ h2) {
    __shared__ float sW2[FH * FC];     // 4 KB
    __shared__ float sp[4][FH];        // per-wave relu'd agg row
    const int t = threadIdx.x;
    #pragma unroll
    for (int i = 0; i < 4; i++) sW2[t + 256 * i] = W2[t + 256 * i];
    __syncthreads();

    int wid = t >> 6;
    int n = blockIdx.x * 4 + wid;
    int lane = t & 63;
    if (n >= NN) return;
    int sg = lane >> 4;        // edge slot 0..3
    int fl = lane & 15;        // feature quad 0..15
    int s0 = row_start[n * K_REP], s1 = row_start[n * K_REP + K_REP];
    float4 A = make_float4(0.f, 0.f, 0.f, 0.f);
    float4 B = make_float4(0.f, 0.f, 0.f, 0.f);
    float4 C = make_float4(0.f, 0.f, 0.f, 0.f);
    float4 D = make_float4(0.f, 0.f, 0.f, 0.f);
    for (int j0 = s0; j0 < s1; j0 += 64) {
        int idx = j0 + lane;
        int sl = (idx < s1) ? csr[idx] : 0;
        int cnt = s1 - j0; if (cnt > 64) cnt = 64;
        int j = 0;
        for (; j + 16 <= cnt; j += 16) {
            int eA = __shfl(sl, j + sg, 64);
            int eB = __shfl(sl, j + 4 + sg, 64);
            int eC = __shfl(sl, j + 8 + sg, 64);
            int eD = __shfl(sl, j + 12 + sg, 64);
            float4 vA = *(const float4*)&h1[eA * FH + fl * 4];
            float4 vB = *(const float4*)&h1[eB * FH + fl * 4];
            float4 vC = *(const float4*)&h1[eC * FH + fl * 4];
            float4 vD = *(const float4*)&h1[eD * FH + fl * 4];
            A = add4(A, vA); B = add4(B, vB);
            C = add4(C, vC); D = add4(D, vD);
        }
        if (j + 8 <= cnt) {
            int eA = __shfl(sl, j + sg, 64);
            int eB = __shfl(sl, j + 4 + sg, 64);
            float4 vA = *(const float4*)&h1[eA * FH + fl * 4];
            float4 vB = *(const float4*)&h1[eB * FH + fl * 4];
            A = add4(A, vA); B = add4(B, vB);
            j += 8;
        }
        if (j + 4 <= cnt) {
            int eA = __shfl(sl, j + sg, 64);
            float4 vA = *(const float4*)&h1[eA * FH + fl * 4];
            A = add4(A, vA);
            j += 4;
        }
        int rem = cnt - j;
        if (rem > 0) {                      // 1..3 edges, mask extra slots
            int jj = j + (sg < rem ? sg : 0);
            int eA = __shfl(sl, jj, 64);
            float wA = (sg < rem) ? 1.f : 0.f;
            float4 vA = *(const float4*)&h1[eA * FH + fl * 4];
            A = fma4(vA, wA, A);
        }
    }
    float4 r = add4(add4(A, B), add4(C, D));
    r = xor_add4(r, 16);
    r = xor_add4(r, 32);                    // all lanes hold full quad sum
    float dn = dinv[n];
    if (sg == 0) {
        float4 self = *(const float4*)&h1[n * FH + fl * 4];   // h1' already scaled
        float4 bq = *(const float4*)&b1[fl * 4];
        float4 p;
        p.x = fmaxf(fmaf(r.x + self.x, dn, bq.x), 0.f);
        p.y = fmaxf(fmaf(r.y + self.y, dn, bq.y), 0.f);
        p.z = fmaxf(fmaf(r.z + self.z, dn, bq.z), 0.f);
        p.w = fmaxf(fmaf(r.w + self.w, dn, bq.w), 0.f);
        *(float4*)&sp[wid][fl * 4] = p;     // wave-local LDS
    }
    __builtin_amdgcn_s_waitcnt(0);          // drain lgkm within wave
    if (lane < FC) {
        float o = 0.f;
        #pragma unroll 8
        for (int k = 0; k < FH; k++)
            o = fmaf(sp[wid][k], sW2[k * FC + lane], o);
        h2[n * FC + lane] = o * dn;         // store h2' = dinv*h2
    }
}

// ---- agg layer2 (h2' prescaled): 16-lane subgroup/node, 16 edges in flight -
__global__ __launch_bounds__(256) void agg2_k(const int* __restrict__ csr,
                                              const int* __restrict__ row_start,
                                              const float* __restrict__ h2,
                                              const float* __restrict__ dinv,
                                              const float* __restrict__ b2,
                                              float* __restrict__ out) {
    const int t = threadIdx.x;
    int n = blockIdx.x * 16 + (t >> 4);
    int l16 = t & 15;
    int base = t & 48;          // subgroup base lane in wave
    int q = (t >> 2) & 3;       // edge slot
    int c = t & 3;              // feature quad
    if (n >= NN) return;
    int s0 = row_start[n * K_REP], s1 = row_start[n * K_REP + K_REP];
    float4 A = make_float4(0.f, 0.f, 0.f, 0.f);
    float4 B = make_float4(0.f, 0.f, 0.f, 0.f);
    float4 C = make_float4(0.f, 0.f, 0.f, 0.f);
    float4 D = make_float4(0.f, 0.f, 0.f, 0.f);
    for (int j0 = s0; j0 < s1; j0 += 16) {
        int idx = j0 + l16;
        int sl = (idx < s1) ? csr[idx] : 0;
        int cnt = s1 - j0; if (cnt > 16) cnt = 16;
        int j = 0;
        if (j + 16 <= cnt) {
            int eA = __shfl(sl, base + j + q, 64);
            int eB = __shfl(sl, base + j + 4 + q, 64);
            int eC = __shfl(sl, base + j + 8 + q, 64);
            int eD = __shfl(sl, base + j + 12 + q, 64);
            float4 vA = *(const float4*)&h2[eA * FC + c * 4];
            float4 vB = *(const float4*)&h2[eB * FC + c * 4];
            float4 vC = *(const float4*)&h2[eC * FC + c * 4];
            float4 vD = *(const float4*)&h2[eD * FC + c * 4];
            A = add4(A, vA); B = add4(B, vB);
            C = add4(C, vC); D = add4(D, vD);
            j += 16;
        }
        if (j + 8 <= cnt) {
            int eA = __shfl(sl, base + j + q, 64);
            int eB = __shfl(sl, base + j + 4 + q, 64);
            float4 vA = *(const float4*)&h2[eA * FC + c * 4];
            float4 vB = *(const float4*)&h2[eB * FC + c * 4];
            A = add4(A, vA); B = add4(B, vB);
            j += 8;
        }
        if (j + 4 <= cnt) {
            int eA = __shfl(sl, base + j + q, 64);
            float4 vA = *(const float4*)&h2[eA * FC + c * 4];
            A = add4(A, vA);
            j += 4;
        }
        int rem = cnt - j;
        if (rem > 0) {
            int jj = base + j + (q < rem ? q : 0);
            int eA = __shfl(sl, jj, 64);
            float wA = (q < rem) ? 1.f : 0.f;
            float4 vA = *(const float4*)&h2[eA * FC + c * 4];
            A = fma4(vA, wA, A);
        }
    }
    float4 r = add4(add4(A, B), add4(C, D));
    r = xor_add4(r, 4);
    r = xor_add4(r, 8);                     // reduce across q within subgroup
    if (q == 0) {
        float dn = dinv[n];
        float4 self = *(const float4*)&h2[n * FC + c * 4];    // h2' already scaled
        float4 bq = *(const float4*)&b2[c * 4];
        float4 p;
        p.x = fmaf(r.x + self.x, dn, bq.x);
        p.y = fmaf(r.y + self.y, dn, bq.y);
        p.z = fmaf(r.z + self.z, dn, bq.z);
        p.w = fmaf(r.w + self.w, dn, bq.w);
        *(float4*)&out[n * FC + c * 4] = p;
    }
}

extern "C" void kernel_launch(void* const* d_in, const int* in_sizes, int n_in,
                              void* d_out, int out_size, void* d_ws, size_t ws_size,
                              hipStream_t stream) {
    const float* x  = (const float*)d_in[0];
    const int*   ei = (const int*)d_in[1];
    const float* W1 = (const float*)d_in[2];
    const float* b1 = (const float*)d_in[3];
    const float* W2 = (const float*)d_in[4];
    const float* b2 = (const float*)d_in[5];
    float* out = (float*)d_out;

    char* ws = (char*)d_ws;
    int*   row_start = (int*)(ws + 0);                         // 3.2 MB + 4
    float* dinv      = (float*)(ws + 3400ull * 1024);          // 400 KB
    int*   flag      = (int*)(ws + 3800ull * 1024);            // 4 B
    int*   partial   = (int*)(ws + 3804ull * 1024);            // 1.6 KB
    unsigned short* Whi = (unsigned short*)(ws + 3840ull * 1024); // 32 KB
    unsigned short* Wlo = (unsigned short*)(ws + 3904ull * 1024); // 32 KB
    int*   deg2      = (int*)(ws + 4096ull * 1024);            // 3.2 MB [memset..scan_out]
    int*   csr       = (int*)(ws + 4096ull * 1024);            // 6.4 MB [fill..agg2] (aliases deg2, dead)
    float* h1        = (float*)(ws + 10400ull * 1024);         // 25.6 MB [fused..agg1g]
    v2i*   packed    = (v2i*)(ws + 35400ull * 1024);           // 12.8 MB [fused..fill]
    float* h2        = (float*)(ws + 35400ull * 1024);         // 6.4 MB  [agg1g..agg2] (aliases packed, dead)

    prep_k<<<9, 256, 0, stream>>>(ei, flag, W1, Whi, Wlo);
    (void)hipMemsetAsync(deg2, 0, (size_t)K_REP * NN * sizeof(int), stream);
    fused_k<<<NB_FUSED, 256, 0, stream>>>(ei, flag, deg2, packed, x, Whi, Wlo, h1);
    scan_sum_k<<<NB_SCAN2, 256, 0, stream>>>(deg2, partial, dinv, h1);
    scan_part_k<<<1, 512, 0, stream>>>(partial);
    scan_out_k<<<NB_SCAN2, 256, 0, stream>>>(deg2, partial, row_start);
    fill_k<<<(NE / 2 + 255) / 256, 256, 0, stream>>>((const int*)packed, row_start, csr);

    agg1g_k<<<(NN + 3) / 4, 256, 0, stream>>>(csr, row_start, h1, dinv, b1, W2, h2);
    agg2_k<<<(NN + 15) / 16, 256, 0, stream>>>(csr, row_start, h2, dinv, b2, out);
}